// Round 10
// baseline (78.255 us; speedup 1.0000x reference)
//
#include <hip/hip_runtime.h>
#include <hip/hip_bf16.h>

#define BATCH 8
#define SEQ   2048
#define DMS   1024
#define KSZ   128
#define OD    1152   // 1024 + 128

typedef unsigned short u16;
typedef unsigned int   u32;
typedef __attribute__((ext_vector_type(4)))  float  f32x4;
typedef __attribute__((ext_vector_type(16))) float  f32x16;
typedef __attribute__((ext_vector_type(8)))  __bf16 bf16x8;

union U128 { uint4 u4; bf16x8 b8; u16 us[8]; u32 u[4]; };

__device__ inline u16 f2bf(float f) {
  union { __bf16 h; u16 u; } c;
  c.h = (__bf16)f;
  return c.u;
}

__device__ inline float fexp2(float x) {
  float r;
  asm("v_exp_f32 %0, %1" : "=v"(r) : "v"(x));
  return r;
}

__device__ inline f32x4 mfma16(bf16x8 a, bf16x8 b, f32x4 c) {
  return __builtin_amdgcn_mfma_f32_16x16x32_bf16(a, b, c, 0, 0, 0);
}
__device__ inline f32x16 mfma32(bf16x8 a, bf16x8 b, f32x16 c) {
  return __builtin_amdgcn_mfma_f32_32x32x16_bf16(a, b, c, 0, 0, 0);
}

__device__ inline uint4 pack8bf(float4 a, float4 b) {
  U128 w;
  w.us[0] = f2bf(a.x); w.us[1] = f2bf(a.y);
  w.us[2] = f2bf(a.z); w.us[3] = f2bf(a.w);
  w.us[4] = f2bf(b.x); w.us[5] = f2bf(b.y);
  w.us[6] = f2bf(b.z); w.us[7] = f2bf(b.w);
  return w.u4;
}

__device__ inline void glds16(const u16* src, u16* ldsDst) {
  __builtin_amdgcn_global_load_lds(
      (const __attribute__((address_space(1))) u32*)src,
      (__attribute__((address_space(3))) u32*)ldsDst, 16, 0, 0);
}

// Fragment-major layouts (per batch, stride 262144 u16 = 512 KB):
//   Kfrag[(t2*8+ks)*512 + hi*256 + l31*8 + j]          = K[t2*32+l31][ks*16+hi*8+j]
//   Vfrag[((t2*4+vb2)*2+th)*512 + hi*256 + l31*8 + j]  = V[t2*32+th*16+hi*8+j][vb2*32+l31]
#define BSTRIDE 262144

// ---------------------------------------------------------------------------
// Kernel 0: prep — [Wk|Wv] f32 -> bf16 tiles, HALF-SPLIT, swizzle baked:
//   Wtiles[ks*16384 + nh*8192 + n1*64 + (kk ^ ((n1&7)<<3))] = W_nh[ks*64+kk][n1]
// ---------------------------------------------------------------------------
__global__ void __launch_bounds__(256) prep_kernel(
    const float* __restrict__ Wk, const float* __restrict__ Wv,
    u16* __restrict__ Wtiles)
{
  int T = blockIdx.x * 256 + threadIdx.x;   // 0..32767
  int n  = T & 255;
  int kc = (T >> 8) * 8;                    // 0..1016 step 8
  int ks = kc >> 6;
  int kk = kc & 63;
  int nh = n >> 7;
  int n1 = n & 127;
  const float* src = nh ? (Wv + n1) : (Wk + n1);
  U128 w;
#pragma unroll
  for (int j = 0; j < 8; ++j) w.us[j] = f2bf(src[(size_t)(kc + j) * KSZ]);
  u16* dst = Wtiles + ks * 16384 + nh * 8192 + n1 * 64 + (kk ^ ((n1 & 7) << 3));
  *(uint4*)dst = w.u4;
}

// ---------------------------------------------------------------------------
// Kernel 0b: cvt — pure streamer. X (f32) -> Xtiles (bf16), LDS-image layout:
//   Xtiles[(rt*16+ks)*4096 + r*64 + (kk ^ ((r&7)<<3))] = bf16(X[rt*64+r][ks*64+kk])
// No barriers, no LDS, no glds — localizes whether streaming is healthy.
// ---------------------------------------------------------------------------
__global__ void __launch_bounds__(256) cvt_kernel(
    const float* __restrict__ X, u16* __restrict__ Xtiles)
{
  int T = blockIdx.x * 256 + threadIdx.x;   // 0..2097151
  int row = T >> 7;
  int c   = T & 127;                        // 8-f32 granule within row
  const float4* xp = (const float4*)(X + (size_t)row * DMS + c * 8);
  float4 a0 = xp[0], a1 = xp[1];
  int rt = row >> 6, r = row & 63, ks = c >> 3, kk0 = (c & 7) * 8;
  u16* dst = Xtiles + (size_t)(rt * 16 + ks) * 4096 + r * 64 + (kk0 ^ ((r & 7) << 3));
  *(uint4*)dst = pack8bf(a0, a1);
}

// ---------------------------------------------------------------------------
// Kernel 1: gemm — m97-clone 2-phase loop; NOTHING in the loop but
// glds (A 8KB + W-half 16KB, both pre-swizzled) + ds_read_b128 + MFMA.
// BM=64, BN=128 (block nh picks K- or V-half), BK=64; 256 thr (4 waves,
// wave = 32-col quarter); grid 512 = 256 row-tiles x 2 halves; LDS 48KB
// dbuf -> 3 blocks/CU. Epilogue: bias + C in LDS -> frag-major stores.
// ---------------------------------------------------------------------------
__global__ void __launch_bounds__(256, 3) gemm_kernel(
    const u16* __restrict__ Xtiles, const u16* __restrict__ Wtiles,
    const float* __restrict__ bk, const float* __restrict__ bv,
    u16* __restrict__ Kfrag, u16* __restrict__ Vfrag)
{
  __shared__ u16 Ab[2][64 * 64];     // 2 x 8 KB
  __shared__ u16 Bt[2][128 * 64];    // 2 x 16 KB

  const int tid  = threadIdx.x;
  const int lane = tid & 63;
  const int w    = tid >> 6;         // 0..3 = n-quarter
  const int l15  = lane & 15;
  const int g    = lane >> 4;

  const int bi = blockIdx.x;
  const int nh = bi & 1;             // 0 = K half, 1 = V half
  const int rt = bi >> 1;            // 0..255 (64-row tile)

  const u16* abase = Xtiles + (size_t)rt * 16 * 4096;
  const u16* wbase = Wtiles + nh * 8192;
  char* AbB = (char*)&Ab[0][0];
  char* BtB = (char*)&Bt[0][0];

  f32x4 acc[4][2];
#pragma unroll
  for (int i = 0; i < 4; ++i)
#pragma unroll
    for (int j = 0; j < 2; ++j) acc[i][j] = (f32x4){0.f, 0.f, 0.f, 0.f};

#define STAGE(K, BUF)                                                          \
  {                                                                            \
    const u16* as = abase + (size_t)(K) * 4096;                                \
    u16* ad = &Ab[BUF][0];                                                     \
    _Pragma("unroll")                                                          \
    for (int i = 0; i < 2; ++i)                                                \
      glds16(as + (w * 2 + i) * 512 + lane * 8, ad + (w * 2 + i) * 512);       \
    const u16* ws = wbase + (size_t)(K) * 16384;                               \
    u16* wd = &Bt[BUF][0];                                                     \
    _Pragma("unroll")                                                          \
    for (int i = 0; i < 4; ++i)                                                \
      glds16(ws + (w * 4 + i) * 512 + lane * 8, wd + (w * 4 + i) * 512);       \
  }

  STAGE(0, 0)
  __syncthreads();

#pragma unroll
  for (int k = 0; k < 16; ++k) {
    const int cur = k & 1, nxt = cur ^ 1;
    if (k < 15) STAGE(k + 1, nxt)
#pragma unroll
    for (int kh = 0; kh < 2; ++kh) {
      bf16x8 af[4], bfr[2];
#pragma unroll
      for (int mf = 0; mf < 4; ++mf) {
        int m = mf * 16 + l15;
        int idx = m * 64 + ((kh * 32 + g * 8) ^ ((m & 7) << 3));
        U128 u; u.u4 = *(uint4*)(AbB + cur * 8192 + idx * 2); af[mf] = u.b8;
      }
#pragma unroll
      for (int nf = 0; nf < 2; ++nf) {
        int n1 = w * 32 + nf * 16 + l15;
        int idx = n1 * 64 + ((kh * 32 + g * 8) ^ ((n1 & 7) << 3));
        U128 u; u.u4 = *(uint4*)(BtB + cur * 16384 + idx * 2); bfr[nf] = u.b8;
      }
#pragma unroll
      for (int mf = 0; mf < 4; ++mf)
#pragma unroll
        for (int nf = 0; nf < 2; ++nf)
          acc[mf][nf] = mfma16(af[mf], bfr[nf], acc[mf][nf]);
    }
    __syncthreads();
  }
#undef STAGE

  // ---- epilogue: bias + C[64][128] (col-swizzled) into Bt[0] ----
  const float* bias_src = nh ? bv : bk;
  u16* Ct = &Bt[0][0];
#pragma unroll
  for (int nf = 0; nf < 2; ++nf) {
    int n1 = w * 32 + nf * 16 + l15;
    float bs = bias_src[n1];
#pragma unroll
    for (int mf = 0; mf < 4; ++mf)
#pragma unroll
      for (int j = 0; j < 4; ++j) {
        int s = mf * 16 + g * 4 + j;
        Ct[s * 128 + (n1 ^ ((s & 7) << 3))] = f2bf(acc[mf][nf][j] + bs);
      }
  }
  __syncthreads();

  const int bb   = rt >> 5;            // batch
  const int tloc = (rt & 31) * 2;      // first 32-row tile within batch

  if (nh == 0) {
    // ---- Kfrag stores ----
#pragma unroll
    for (int p = 0; p < 2; ++p) {
      int s   = (tid >> 3) + p * 32;   // 0..63
      int ks2 = tid & 7;
      int t2  = tloc + (s >> 5);
      int l31 = s & 31;
      u16* dst = Kfrag + (size_t)bb * BSTRIDE + (size_t)(t2 * 8 + ks2) * 512 + l31 * 8;
#pragma unroll
      for (int hi2 = 0; hi2 < 2; ++hi2) {
        int n1 = ks2 * 16 + hi2 * 8;
        uint4 v = *(const uint4*)&Ct[s * 128 + (n1 ^ ((s & 7) << 3))];
        *(uint4*)(dst + hi2 * 256) = v;
      }
    }
  } else {
    // ---- Vfrag stores (transpose out of C) ----
    int l31 = tid & 31;
    int vb2 = (tid >> 5) & 3;
    int th  = tid >> 7;                // 0..1
#pragma unroll
    for (int p = 0; p < 2; ++p) {
      int t2 = tloc + p;
#pragma unroll
      for (int hi = 0; hi < 2; ++hi) {
        U128 wv;
#pragma unroll
        for (int j = 0; j < 8; ++j) {
          int s = p * 32 + th * 16 + hi * 8 + j;
          wv.us[j] = Ct[s * 128 + ((vb2 * 32 + l31) ^ ((s & 7) << 3))];
        }
        u16* dst = Vfrag + (size_t)bb * BSTRIDE +
                   (size_t)((t2 * 4 + vb2) * 2 + th) * 512 + hi * 256 + l31 * 8;
        *(uint4*)dst = wv.u4;
      }
    }
  }
}

// ---------------------------------------------------------------------------
// Kernel 2: causal flash attention + TAIL passthrough copy (unchanged R9).
// ---------------------------------------------------------------------------
__global__ void __launch_bounds__(256, 2) attn_kernel(
    const u16* __restrict__ Kfrag, const u16* __restrict__ Vfrag,
    const float* __restrict__ X, float* __restrict__ out)
{
  __shared__ float Om[4][128][33];   // [slice][v][q] partial O^T
  __shared__ float Ml[4][2][32];     // [slice][m|l][q]
  __shared__ float Wm[4][32];        // merge weights
  __shared__ float Li[32];           // 1/L

  const int tid  = threadIdx.x;
  const int lane = tid & 63;
  const int w    = tid >> 6;         // KV slice 0..3
  const int l31  = lane & 31;
  const int hi   = lane >> 5;

  const int bi = blockIdx.x;
  const int b  = bi & 7;
  const int qt = (bi < 256) ? (63 - (bi >> 3)) : ((bi >> 3) - 32);
  const int q0 = qt * 32;

  const u16* Kb = Kfrag + (size_t)b * BSTRIDE;
  const u16* Vb = Vfrag + (size_t)b * BSTRIDE;
  const int loff = hi * 256 + l31 * 8;   // lane offset within a 512-u16 frag

  bf16x8 qf[8];
  {
    const u16* qp = Kb + (size_t)(qt * 8) * 512 + loff;
#pragma unroll
    for (int ks = 0; ks < 8; ++ks) {
      U128 u; u.u4 = *(const uint4*)(qp + ks * 512); qf[ks] = u.b8;
    }
  }

  f32x16 o[4];
#pragma unroll
  for (int vb2 = 0; vb2 < 4; ++vb2)
#pragma unroll
    for (int i = 0; i < 16; ++i) o[vb2][i] = 0.f;

  float mrun = -3.0e38f, lsum = 0.f;
  const float SC  = 0.08838834764831845f;   // 1/sqrt(128)
  const float L2E = 1.44269504088896341f;

  bf16x8 kf[8];
  {
    int ti0 = (w <= qt) ? w : 0;
    const u16* kp = Kb + (size_t)(ti0 * 8) * 512 + loff;
#pragma unroll
    for (int ks = 0; ks < 8; ++ks) {
      U128 u; u.u4 = *(const uint4*)(kp + ks * 512); kf[ks] = u.b8;
    }
  }

  for (int ti = w; ti <= qt; ti += 4) {
    bf16x8 vf[4][2];
    {
      const u16* vp = Vb + (size_t)(ti * 8) * 512 + loff;
#pragma unroll
      for (int vb2 = 0; vb2 < 4; ++vb2)
#pragma unroll
        for (int th = 0; th < 2; ++th) {
          U128 u; u.u4 = *(const uint4*)(vp + (vb2 * 2 + th) * 512);
          vf[vb2][th] = u.b8;
        }
    }
    f32x16 s;
#pragma unroll
    for (int i = 0; i < 16; ++i) s[i] = 0.f;
#pragma unroll
    for (int ks = 0; ks < 8; ++ks) s = mfma32(kf[ks], qf[ks], s);
    {
      int tin = (ti + 4 <= qt) ? ti + 4 : ti;
      const u16* kp = Kb + (size_t)(tin * 8) * 512 + loff;
#pragma unroll
      for (int ks = 0; ks < 8; ++ks) {
        U128 u; u.u4 = *(const uint4*)(kp + ks * 512); kf[ks] = u.b8;
      }
    }
    float sv[16];
#pragma unroll
    for (int r = 0; r < 16; ++r) sv[r] = s[r] * SC;
    if (ti == qt) {
#pragma unroll
      for (int r = 0; r < 16; ++r) {
        int toff = (r & 3) + 8 * (r >> 2) + 4 * hi;
        if (toff > l31) sv[r] = -3.0e38f;
      }
    }
    float mx = sv[0];
#pragma unroll
    for (int r = 1; r < 16; ++r) mx = fmaxf(mx, sv[r]);
    mx = fmaxf(mx, __shfl_xor(mx, 32));
    float p[16];
    float ps = 0.f;
    if (__all(mx - mrun <= 8.0f)) {
#pragma unroll
      for (int r = 0; r < 16; ++r) { p[r] = fexp2((sv[r] - mrun) * L2E); ps += p[r]; }
      ps += __shfl_xor(ps, 32);
      lsum += ps;
    } else {
      float mnew = fmaxf(mrun, mx);
      float al = fexp2((mrun - mnew) * L2E);
#pragma unroll
      for (int r = 0; r < 16; ++r) { p[r] = fexp2((sv[r] - mnew) * L2E); ps += p[r]; }
      ps += __shfl_xor(ps, 32);
      lsum = lsum * al + ps;
      mrun = mnew;
#pragma unroll
      for (int vb2 = 0; vb2 < 4; ++vb2)
#pragma unroll
        for (int i = 0; i < 16; ++i) o[vb2][i] *= al;
    }
    u32 c01 = (u32)f2bf(p[0])  | ((u32)f2bf(p[1])  << 16);
    u32 c23 = (u32)f2bf(p[2])  | ((u32)f2bf(p[3])  << 16);
    u32 c45 = (u32)f2bf(p[4])  | ((u32)f2bf(p[5])  << 16);
    u32 c67 = (u32)f2bf(p[6])  | ((u32)f2bf(p[7])  << 16);
    u32 c89 = (u32)f2bf(p[8])  | ((u32)f2bf(p[9])  << 16);
    u32 cAB = (u32)f2bf(p[10]) | ((u32)f2bf(p[11]) << 16);
    u32 cCD = (u32)f2bf(p[12]) | ((u32)f2bf(p[13]) << 16);
    u32 cEF = (u32)f2bf(p[14]) | ((u32)f2bf(p[15]) << 16);
    u32 d01 = __shfl_xor(c01, 32);
    u32 d23 = __shfl_xor(c23, 32);
    u32 d45 = __shfl_xor(c45, 32);
    u32 d67 = __shfl_xor(c67, 32);
    u32 d89 = __shfl_xor(c89, 32);
    u32 dAB = __shfl_xor(cAB, 32);
    u32 dCD = __shfl_xor(cCD, 32);
    u32 dEF = __shfl_xor(cEF, 32);
    U128 pf1, pf2;
    pf1.u[0] = hi ? d45 : c01;
    pf1.u[1] = hi ? d67 : c23;
    pf1.u[2] = hi ? c45 : d01;
    pf1.u[3] = hi ? c67 : d23;
    pf2.u[0] = hi ? dCD : c89;
    pf2.u[1] = hi ? dEF : cAB;
    pf2.u[2] = hi ? cCD : d89;
    pf2.u[3] = hi ? cEF : dAB;
#pragma unroll
    for (int vb2 = 0; vb2 < 4; ++vb2) {
      o[vb2] = mfma32(vf[vb2][0], pf1.b8, o[vb2]);
      o[vb2] = mfma32(vf[vb2][1], pf2.b8, o[vb2]);
    }
  }

  // ---- publish partials ----
#pragma unroll
  for (int vb2 = 0; vb2 < 4; ++vb2)
#pragma unroll
    for (int r = 0; r < 16; ++r) {
      int v = vb2 * 32 + (r & 3) + 8 * (r >> 2) + 4 * hi;
      Om[w][v][l31] = o[vb2][r];
    }
  if (lane < 32) {
    Ml[w][0][l31] = mrun;
    Ml[w][1][l31] = lsum;
  }
  __syncthreads();

  if (tid < 32) {
    float m0 = Ml[0][0][tid], m1 = Ml[1][0][tid];
    float m2 = Ml[2][0][tid], m3 = Ml[3][0][tid];
    float M  = fmaxf(fmaxf(m0, m1), fmaxf(m2, m3));
    float w0 = fexp2((m0 - M) * L2E), w1 = fexp2((m1 - M) * L2E);
    float w2 = fexp2((m2 - M) * L2E), w3 = fexp2((m3 - M) * L2E);
    float L  = Ml[0][1][tid] * w0 + Ml[1][1][tid] * w1 +
               Ml[2][1][tid] * w2 + Ml[3][1][tid] * w3;
    Wm[0][tid] = w0; Wm[1][tid] = w1; Wm[2][tid] = w2; Wm[3][tid] = w3;
    Li[tid] = 1.f / L;
  }
  __syncthreads();

  {
    const int q = tid >> 3;
    const int vbase = (tid & 7) * 16;
    float wq0 = Wm[0][q], wq1 = Wm[1][q], wq2 = Wm[2][q], wq3 = Wm[3][q];
    float li = Li[q];
    float* orow = out + (size_t)(b * SEQ + q0 + q) * OD + 1024 + vbase;
#pragma unroll
    for (int i = 0; i < 16; i += 4) {
      float4 res;
      res.x = (Om[0][vbase + i + 0][q] * wq0 + Om[1][vbase + i + 0][q] * wq1 +
               Om[2][vbase + i + 0][q] * wq2 + Om[3][vbase + i + 0][q] * wq3) * li;
      res.y = (Om[0][vbase + i + 1][q] * wq0 + Om[1][vbase + i + 1][q] * wq1 +
               Om[2][vbase + i + 1][q] * wq2 + Om[3][vbase + i + 1][q] * wq3) * li;
      res.z = (Om[0][vbase + i + 2][q] * wq0 + Om[1][vbase + i + 2][q] * wq1 +
               Om[2][vbase + i + 2][q] * wq2 + Om[3][vbase + i + 2][q] * wq3) * li;
      res.w = (Om[0][vbase + i + 3][q] * wq0 + Om[1][vbase + i + 3][q] * wq1 +
               Om[2][vbase + i + 3][q] * wq2 + Om[3][vbase + i + 3][q] * wq3) * li;
      *(float4*)(orow + i) = res;
    }
  }

  // ---- TAIL passthrough copy: out[:, :1024] = X for this block's 32 rows ----
  {
#pragma unroll
    for (int r0 = 0; r0 < 32; r0 += 8) {
      float4 t[8];
#pragma unroll
      for (int j = 0; j < 8; ++j)
        t[j] = *((const float4*)(X + (size_t)(b * SEQ + q0 + r0 + j) * DMS) + tid);
#pragma unroll
      for (int j = 0; j < 8; ++j)
        *((float4*)(out + (size_t)(b * SEQ + q0 + r0 + j) * OD) + tid) = t[j];
    }
  }
}

extern "C" void kernel_launch(void* const* d_in, const int* in_sizes, int n_in,
                              void* d_out, int out_size, void* d_ws, size_t ws_size,
                              hipStream_t stream)
{
  const float* X  = (const float*)d_in[0];
  const float* Wk = (const float*)d_in[1];
  const float* bk = (const float*)d_in[2];
  const float* Wv = (const float*)d_in[3];
  const float* bv = (const float*)d_in[4];
  float* out = (float*)d_out;

  u16* Kfrag  = (u16*)d_ws;                                 // 4 MB
  u16* Vfrag  = Kfrag + (size_t)BATCH * BSTRIDE;            // 4 MB
  u16* Wtiles = Vfrag + (size_t)BATCH * BSTRIDE;            // 512 KB
  u16* Xtiles = Wtiles + (size_t)262144;                    // 32 MB

  prep_kernel<<<dim3(128), dim3(256), 0, stream>>>(Wk, Wv, Wtiles);
  cvt_kernel<<<dim3(8192), dim3(256), 0, stream>>>(X, Xtiles);
  gemm_kernel<<<dim3(512), dim3(256), 0, stream>>>(Xtiles, Wtiles, bk, bv, Kfrag, Vfrag);
  attn_kernel<<<dim3(512), dim3(256), 0, stream>>>(Kfrag, Vfrag, X, out);
}

// Round 11
// 74.829 us; speedup vs baseline: 1.0458x; 1.0458x over previous
//
#include <hip/hip_runtime.h>
#include <hip/hip_bf16.h>

#define BATCH 8
#define SEQ   2048
#define DMS   1024
#define KSZ   128
#define OD    1152   // 1024 + 128

typedef unsigned short u16;
typedef unsigned int   u32;
typedef __attribute__((ext_vector_type(4)))  float  f32x4;
typedef __attribute__((ext_vector_type(16))) float  f32x16;
typedef __attribute__((ext_vector_type(8)))  __bf16 bf16x8;

union U128 { uint4 u4; bf16x8 b8; u16 us[8]; u32 u[4]; };

__device__ inline u16 f2bf(float f) {
  union { __bf16 h; u16 u; } c;
  c.h = (__bf16)f;
  return c.u;
}

__device__ inline float fexp2(float x) {
  float r;
  asm("v_exp_f32 %0, %1" : "=v"(r) : "v"(x));
  return r;
}

__device__ inline f32x4 mfma16(bf16x8 a, bf16x8 b, f32x4 c) {
  return __builtin_amdgcn_mfma_f32_16x16x32_bf16(a, b, c, 0, 0, 0);
}
__device__ inline f32x16 mfma32(bf16x8 a, bf16x8 b, f32x16 c) {
  return __builtin_amdgcn_mfma_f32_32x32x16_bf16(a, b, c, 0, 0, 0);
}

__device__ inline uint4 pack8bf(float4 a, float4 b) {
  U128 w;
  w.us[0] = f2bf(a.x); w.us[1] = f2bf(a.y);
  w.us[2] = f2bf(a.z); w.us[3] = f2bf(a.w);
  w.us[4] = f2bf(b.x); w.us[5] = f2bf(b.y);
  w.us[6] = f2bf(b.z); w.us[7] = f2bf(b.w);
  return w.u4;
}

__device__ inline void glds16(const u16* src, u16* ldsDst) {
  __builtin_amdgcn_global_load_lds(
      (const __attribute__((address_space(1))) u32*)src,
      (__attribute__((address_space(3))) u32*)ldsDst, 16, 0, 0);
}

// Fragment-major layouts (per batch, stride 262144 u16 = 512 KB):
//   Kfrag[(t2*8+ks)*512 + hi*256 + l31*8 + j]          = K[t2*32+l31][ks*16+hi*8+j]
//   Vfrag[((t2*4+vb2)*2+th)*512 + hi*256 + l31*8 + j]  = V[t2*32+th*16+hi*8+j][vb2*32+l31]
#define BSTRIDE 262144

// ---------------------------------------------------------------------------
// Kernel 0: prep — [Wk|Wv] f32 -> bf16 SLAB images (8 slabs x 64KB).
//   Wslabs[s*32768 + n*128 + (kk ^ ((n&7)<<3))] = W[s*128 + kk][n]
//   (n in [0,256): col, Wk|Wv concat; kk in [0,128): k within slab)
// ---------------------------------------------------------------------------
__global__ void __launch_bounds__(256) prep_kernel(
    const float* __restrict__ Wk, const float* __restrict__ Wv,
    u16* __restrict__ Wslabs)
{
  int T = blockIdx.x * 256 + threadIdx.x;   // 0..32767
  int n  = T & 255;
  int kc = (T >> 8) * 8;                    // global k, 0..1016 step 8
  int s  = kc >> 7;
  int kk = kc & 127;
  const float* src = (n < 128) ? (Wk + n) : (Wv + (n - 128));
  U128 w;
#pragma unroll
  for (int j = 0; j < 8; ++j) w.us[j] = f2bf(src[(size_t)(kc + j) * KSZ]);
  u16* dst = Wslabs + s * 32768 + n * 128 + (kk ^ ((n & 7) << 3));
  *(uint4*)dst = w.u4;
}

// ---------------------------------------------------------------------------
// Kernel 1: slab-GEMM — 16 barriers TOTAL per block (2 per slab), not 2 per
// k-step. (R6/R9/R10 invariant: per-k-step-barriered glds loops cost ~2500
// cyc/step regardless of content; m233's 2-phase stall. Fix = bigger steps.)
// Grid 256 (1 block/CU), 256 thr (4 waves), 64 rows/block, full 256 cols.
// Per slab s (K=128): bar -> glds 64KB W-slab + issue X reg-loads -> bar ->
// 4 ks x 16 nf MFMA from LDS. Epilogue: bias + C in LDS (reuse slab buffer)
// -> frag-major Kfrag/Vfrag stores.
// ---------------------------------------------------------------------------
__global__ void __launch_bounds__(256, 1) gemm_kernel(
    const float* __restrict__ X, const u16* __restrict__ Wslabs,
    const float* __restrict__ bk, const float* __restrict__ bv,
    u16* __restrict__ Kfrag, u16* __restrict__ Vfrag)
{
  __shared__ u16 Ws[256 * 128];   // 64 KB: one W slab; reused as C at the end

  const int tid  = threadIdx.x;
  const int lane = tid & 63;
  const int wv   = tid >> 6;      // 0..3
  const int l15  = lane & 15;
  const int g    = lane >> 4;
  const int m0   = blockIdx.x * 64;

  const float* xrow = X + (size_t)(m0 + wv * 16 + l15) * DMS + g * 8;

  f32x4 acc[16];
#pragma unroll
  for (int nf = 0; nf < 16; ++nf) acc[nf] = (f32x4){0.f, 0.f, 0.f, 0.f};

#pragma unroll 1
  for (int s = 0; s < 8; ++s) {
    __syncthreads();   // slab buffer free (prev compute done)
    // ---- stage W slab s: 64KB linear glds ----
    {
      const u16* ws = Wslabs + s * 32768 + tid * 8;
      u16* wd = Ws + tid * 8;
#pragma unroll
      for (int c = 0; c < 16; ++c) glds16(ws + c * 2048, wd + c * 2048);
    }
    // ---- X reg-loads for this slab (drained at the same barrier) ----
    float4 xv[8];
#pragma unroll
    for (int ks = 0; ks < 4; ++ks) {
      xv[ks * 2]     = *(const float4*)(xrow + s * 128 + ks * 32);
      xv[ks * 2 + 1] = *(const float4*)(xrow + s * 128 + ks * 32 + 4);
    }
    __syncthreads();   // slab staged + X arrived
    // ---- compute: 4 ks x 16 nf ----
#pragma unroll
    for (int ks = 0; ks < 4; ++ks) {
      U128 aw; aw.u4 = pack8bf(xv[ks * 2], xv[ks * 2 + 1]);
#pragma unroll
      for (int nf = 0; nf < 16; ++nf) {
        int n = nf * 16 + l15;
        int idx = n * 128 + ((ks * 32 + g * 8) ^ ((n & 7) << 3));
        U128 u; u.u4 = *(const uint4*)(Ws + idx);
        acc[nf] = mfma16(aw.b8, u.b8, acc[nf]);
      }
    }
  }

  __syncthreads();   // all slab reads done; reuse Ws as C[64][256] col-swizzled
#pragma unroll
  for (int nf = 0; nf < 16; ++nf) {
    int n = nf * 16 + l15;
    float bs = (n < 128) ? bk[n] : bv[n - 128];
#pragma unroll
    for (int j = 0; j < 4; ++j) {
      int srow = wv * 16 + g * 4 + j;
      Ws[srow * 256 + (n ^ ((srow & 7) << 3))] = f2bf(acc[nf][j] + bs);
    }
  }
  __syncthreads();

  const int bb   = m0 >> 11;            // batch
  const int tloc = (m0 & 2047) >> 5;    // first 32-row tile within batch

  // ---- Kfrag stores: 4 uint4/thread ----
  {
    int sl  = tid >> 2;                 // 0..63 block row
    int t2  = tloc + (sl >> 5);
    int l31 = sl & 31;
#pragma unroll
    for (int h = 0; h < 2; ++h) {
      int ks2 = (tid & 3) * 2 + h;      // 0..7
      u16* dst = Kfrag + (size_t)bb * BSTRIDE + (size_t)(t2 * 8 + ks2) * 512 + l31 * 8;
#pragma unroll
      for (int hi2 = 0; hi2 < 2; ++hi2) {
        int n = ks2 * 16 + hi2 * 8;
        uint4 v = *(const uint4*)&Ws[sl * 256 + (n ^ ((sl & 7) << 3))];
        *(uint4*)(dst + hi2 * 256) = v;
      }
    }
  }
  // ---- Vfrag stores (transpose out of C): 4 uint4/thread ----
  {
    int l31 = tid & 31;
    int vb2 = (tid >> 5) & 3;
    int th  = (tid >> 7) & 1;
    int n   = 128 + vb2 * 32 + l31;
#pragma unroll
    for (int p = 0; p < 2; ++p) {
      int t2 = tloc + p;
#pragma unroll
      for (int hi = 0; hi < 2; ++hi) {
        U128 wvv;
#pragma unroll
        for (int j = 0; j < 8; ++j) {
          int srow = p * 32 + th * 16 + hi * 8 + j;
          wvv.us[j] = Ws[srow * 256 + (n ^ ((srow & 7) << 3))];
        }
        u16* dst = Vfrag + (size_t)bb * BSTRIDE +
                   (size_t)((t2 * 4 + vb2) * 2 + th) * 512 + hi * 256 + l31 * 8;
        *(uint4*)dst = wvv.u4;
      }
    }
  }
}

// ---------------------------------------------------------------------------
// Kernel 2: causal flash attention + TAIL passthrough copy (unchanged R9).
// ---------------------------------------------------------------------------
__global__ void __launch_bounds__(256, 2) attn_kernel(
    const u16* __restrict__ Kfrag, const u16* __restrict__ Vfrag,
    const float* __restrict__ X, float* __restrict__ out)
{
  __shared__ float Om[4][128][33];   // [slice][v][q] partial O^T
  __shared__ float Ml[4][2][32];     // [slice][m|l][q]
  __shared__ float Wm[4][32];        // merge weights
  __shared__ float Li[32];           // 1/L

  const int tid  = threadIdx.x;
  const int lane = tid & 63;
  const int w    = tid >> 6;         // KV slice 0..3
  const int l31  = lane & 31;
  const int hi   = lane >> 5;

  const int bi = blockIdx.x;
  const int b  = bi & 7;
  const int qt = (bi < 256) ? (63 - (bi >> 3)) : ((bi >> 3) - 32);
  const int q0 = qt * 32;

  const u16* Kb = Kfrag + (size_t)b * BSTRIDE;
  const u16* Vb = Vfrag + (size_t)b * BSTRIDE;
  const int loff = hi * 256 + l31 * 8;   // lane offset within a 512-u16 frag

  bf16x8 qf[8];
  {
    const u16* qp = Kb + (size_t)(qt * 8) * 512 + loff;
#pragma unroll
    for (int ks = 0; ks < 8; ++ks) {
      U128 u; u.u4 = *(const uint4*)(qp + ks * 512); qf[ks] = u.b8;
    }
  }

  f32x16 o[4];
#pragma unroll
  for (int vb2 = 0; vb2 < 4; ++vb2)
#pragma unroll
    for (int i = 0; i < 16; ++i) o[vb2][i] = 0.f;

  float mrun = -3.0e38f, lsum = 0.f;
  const float SC  = 0.08838834764831845f;   // 1/sqrt(128)
  const float L2E = 1.44269504088896341f;

  bf16x8 kf[8];
  {
    int ti0 = (w <= qt) ? w : 0;
    const u16* kp = Kb + (size_t)(ti0 * 8) * 512 + loff;
#pragma unroll
    for (int ks = 0; ks < 8; ++ks) {
      U128 u; u.u4 = *(const uint4*)(kp + ks * 512); kf[ks] = u.b8;
    }
  }

  for (int ti = w; ti <= qt; ti += 4) {
    bf16x8 vf[4][2];
    {
      const u16* vp = Vb + (size_t)(ti * 8) * 512 + loff;
#pragma unroll
      for (int vb2 = 0; vb2 < 4; ++vb2)
#pragma unroll
        for (int th = 0; th < 2; ++th) {
          U128 u; u.u4 = *(const uint4*)(vp + (vb2 * 2 + th) * 512);
          vf[vb2][th] = u.b8;
        }
    }
    f32x16 s;
#pragma unroll
    for (int i = 0; i < 16; ++i) s[i] = 0.f;
#pragma unroll
    for (int ks = 0; ks < 8; ++ks) s = mfma32(kf[ks], qf[ks], s);
    {
      int tin = (ti + 4 <= qt) ? ti + 4 : ti;
      const u16* kp = Kb + (size_t)(tin * 8) * 512 + loff;
#pragma unroll
      for (int ks = 0; ks < 8; ++ks) {
        U128 u; u.u4 = *(const uint4*)(kp + ks * 512); kf[ks] = u.b8;
      }
    }
    float sv[16];
#pragma unroll
    for (int r = 0; r < 16; ++r) sv[r] = s[r] * SC;
    if (ti == qt) {
#pragma unroll
      for (int r = 0; r < 16; ++r) {
        int toff = (r & 3) + 8 * (r >> 2) + 4 * hi;
        if (toff > l31) sv[r] = -3.0e38f;
      }
    }
    float mx = sv[0];
#pragma unroll
    for (int r = 1; r < 16; ++r) mx = fmaxf(mx, sv[r]);
    mx = fmaxf(mx, __shfl_xor(mx, 32));
    float p[16];
    float ps = 0.f;
    if (__all(mx - mrun <= 8.0f)) {
#pragma unroll
      for (int r = 0; r < 16; ++r) { p[r] = fexp2((sv[r] - mrun) * L2E); ps += p[r]; }
      ps += __shfl_xor(ps, 32);
      lsum += ps;
    } else {
      float mnew = fmaxf(mrun, mx);
      float al = fexp2((mrun - mnew) * L2E);
#pragma unroll
      for (int r = 0; r < 16; ++r) { p[r] = fexp2((sv[r] - mnew) * L2E); ps += p[r]; }
      ps += __shfl_xor(ps, 32);
      lsum = lsum * al + ps;
      mrun = mnew;
#pragma unroll
      for (int vb2 = 0; vb2 < 4; ++vb2)
#pragma unroll
        for (int i = 0; i < 16; ++i) o[vb2][i] *= al;
    }
    u32 c01 = (u32)f2bf(p[0])  | ((u32)f2bf(p[1])  << 16);
    u32 c23 = (u32)f2bf(p[2])  | ((u32)f2bf(p[3])  << 16);
    u32 c45 = (u32)f2bf(p[4])  | ((u32)f2bf(p[5])  << 16);
    u32 c67 = (u32)f2bf(p[6])  | ((u32)f2bf(p[7])  << 16);
    u32 c89 = (u32)f2bf(p[8])  | ((u32)f2bf(p[9])  << 16);
    u32 cAB = (u32)f2bf(p[10]) | ((u32)f2bf(p[11]) << 16);
    u32 cCD = (u32)f2bf(p[12]) | ((u32)f2bf(p[13]) << 16);
    u32 cEF = (u32)f2bf(p[14]) | ((u32)f2bf(p[15]) << 16);
    u32 d01 = __shfl_xor(c01, 32);
    u32 d23 = __shfl_xor(c23, 32);
    u32 d45 = __shfl_xor(c45, 32);
    u32 d67 = __shfl_xor(c67, 32);
    u32 d89 = __shfl_xor(c89, 32);
    u32 dAB = __shfl_xor(cAB, 32);
    u32 dCD = __shfl_xor(cCD, 32);
    u32 dEF = __shfl_xor(cEF, 32);
    U128 pf1, pf2;
    pf1.u[0] = hi ? d45 : c01;
    pf1.u[1] = hi ? d67 : c23;
    pf1.u[2] = hi ? c45 : d01;
    pf1.u[3] = hi ? c67 : d23;
    pf2.u[0] = hi ? dCD : c89;
    pf2.u[1] = hi ? dEF : cAB;
    pf2.u[2] = hi ? cCD : d89;
    pf2.u[3] = hi ? cEF : dAB;
#pragma unroll
    for (int vb2 = 0; vb2 < 4; ++vb2) {
      o[vb2] = mfma32(vf[vb2][0], pf1.b8, o[vb2]);
      o[vb2] = mfma32(vf[vb2][1], pf2.b8, o[vb2]);
    }
  }

  // ---- publish partials ----
#pragma unroll
  for (int vb2 = 0; vb2 < 4; ++vb2)
#pragma unroll
    for (int r = 0; r < 16; ++r) {
      int v = vb2 * 32 + (r & 3) + 8 * (r >> 2) + 4 * hi;
      Om[w][v][l31] = o[vb2][r];
    }
  if (lane < 32) {
    Ml[w][0][l31] = mrun;
    Ml[w][1][l31] = lsum;
  }
  __syncthreads();

  if (tid < 32) {
    float m0 = Ml[0][0][tid], m1 = Ml[1][0][tid];
    float m2 = Ml[2][0][tid], m3 = Ml[3][0][tid];
    float M  = fmaxf(fmaxf(m0, m1), fmaxf(m2, m3));
    float w0 = fexp2((m0 - M) * L2E), w1 = fexp2((m1 - M) * L2E);
    float w2 = fexp2((m2 - M) * L2E), w3 = fexp2((m3 - M) * L2E);
    float L  = Ml[0][1][tid] * w0 + Ml[1][1][tid] * w1 +
               Ml[2][1][tid] * w2 + Ml[3][1][tid] * w3;
    Wm[0][tid] = w0; Wm[1][tid] = w1; Wm[2][tid] = w2; Wm[3][tid] = w3;
    Li[tid] = 1.f / L;
  }
  __syncthreads();

  {
    const int q = tid >> 3;
    const int vbase = (tid & 7) * 16;
    float wq0 = Wm[0][q], wq1 = Wm[1][q], wq2 = Wm[2][q], wq3 = Wm[3][q];
    float li = Li[q];
    float* orow = out + (size_t)(b * SEQ + q0 + q) * OD + 1024 + vbase;
#pragma unroll
    for (int i = 0; i < 16; i += 4) {
      float4 res;
      res.x = (Om[0][vbase + i + 0][q] * wq0 + Om[1][vbase + i + 0][q] * wq1 +
               Om[2][vbase + i + 0][q] * wq2 + Om[3][vbase + i + 0][q] * wq3) * li;
      res.y = (Om[0][vbase + i + 1][q] * wq0 + Om[1][vbase + i + 1][q] * wq1 +
               Om[2][vbase + i + 1][q] * wq2 + Om[3][vbase + i + 1][q] * wq3) * li;
      res.z = (Om[0][vbase + i + 2][q] * wq0 + Om[1][vbase + i + 2][q] * wq1 +
               Om[2][vbase + i + 2][q] * wq2 + Om[3][vbase + i + 2][q] * wq3) * li;
      res.w = (Om[0][vbase + i + 3][q] * wq0 + Om[1][vbase + i + 3][q] * wq1 +
               Om[2][vbase + i + 3][q] * wq2 + Om[3][vbase + i + 3][q] * wq3) * li;
      *(float4*)(orow + i) = res;
    }
  }

  // ---- TAIL passthrough copy: out[:, :1024] = X for this block's 32 rows ----
  {
#pragma unroll
    for (int r0 = 0; r0 < 32; r0 += 8) {
      float4 t[8];
#pragma unroll
      for (int j = 0; j < 8; ++j)
        t[j] = *((const float4*)(X + (size_t)(b * SEQ + q0 + r0 + j) * DMS) + tid);
#pragma unroll
      for (int j = 0; j < 8; ++j)
        *((float4*)(out + (size_t)(b * SEQ + q0 + r0 + j) * OD) + tid) = t[j];
    }
  }
}

extern "C" void kernel_launch(void* const* d_in, const int* in_sizes, int n_in,
                              void* d_out, int out_size, void* d_ws, size_t ws_size,
                              hipStream_t stream)
{
  const float* X  = (const float*)d_in[0];
  const float* Wk = (const float*)d_in[1];
  const float* bk = (const float*)d_in[2];
  const float* Wv = (const float*)d_in[3];
  const float* bv = (const float*)d_in[4];
  float* out = (float*)d_out;

  u16* Kfrag  = (u16*)d_ws;                                 // 4 MB
  u16* Vfrag  = Kfrag + (size_t)BATCH * BSTRIDE;            // 4 MB
  u16* Wslabs = Vfrag + (size_t)BATCH * BSTRIDE;            // 512 KB

  prep_kernel<<<dim3(128), dim3(256), 0, stream>>>(Wk, Wv, Wslabs);
  gemm_kernel<<<dim3(256), dim3(256), 0, stream>>>(X, Wslabs, bk, bv, Kfrag, Vfrag);
  attn_kernel<<<dim3(512), dim3(256), 0, stream>>>(Kfrag, Vfrag, X, out);
}

// Round 12
// 67.850 us; speedup vs baseline: 1.1533x; 1.1029x over previous
//
#include <hip/hip_runtime.h>
#include <hip/hip_bf16.h>

#define BATCH 8
#define SEQ   2048
#define DMS   1024
#define KSZ   128
#define OD    1152   // 1024 + 128

typedef unsigned short u16;
typedef unsigned int   u32;
typedef __attribute__((ext_vector_type(4)))  float  f32x4;
typedef __attribute__((ext_vector_type(16))) float  f32x16;
typedef __attribute__((ext_vector_type(8)))  __bf16 bf16x8;

union U128 { uint4 u4; bf16x8 b8; u16 us[8]; u32 u[4]; };

__device__ inline u16 f2bf(float f) {
  union { __bf16 h; u16 u; } c;
  c.h = (__bf16)f;
  return c.u;
}

__device__ inline float fexp2(float x) {
  float r;
  asm("v_exp_f32 %0, %1" : "=v"(r) : "v"(x));
  return r;
}

__device__ inline f32x4 mfma16(bf16x8 a, bf16x8 b, f32x4 c) {
  return __builtin_amdgcn_mfma_f32_16x16x32_bf16(a, b, c, 0, 0, 0);
}
__device__ inline f32x16 mfma32(bf16x8 a, bf16x8 b, f32x16 c) {
  return __builtin_amdgcn_mfma_f32_32x32x16_bf16(a, b, c, 0, 0, 0);
}

__device__ inline uint4 pack8bf(float4 a, float4 b) {
  U128 w;
  w.us[0] = f2bf(a.x); w.us[1] = f2bf(a.y);
  w.us[2] = f2bf(a.z); w.us[3] = f2bf(a.w);
  w.us[4] = f2bf(b.x); w.us[5] = f2bf(b.y);
  w.us[6] = f2bf(b.z); w.us[7] = f2bf(b.w);
  return w.u4;
}

// Fragment-major layouts (per batch, stride 262144 u16 = 512 KB):
//   Kfrag[(t2*8+ks)*512 + hi*256 + l31*8 + j]          = K[t2*32+l31][ks*16+hi*8+j]
//   Vfrag[((t2*4+vb2)*2+th)*512 + hi*256 + l31*8 + j]  = V[t2*32+th*16+hi*8+j][vb2*32+l31]
#define BSTRIDE 262144

// W fragment layout (B-operand of mfma16, frag-major; R7-verified):
//   Wfrag[(ks*1024 + nf*64 + lane)*8 + j] = W[ks*32 + (lane>>4)*8 + j][nf*16 + (lane&15)]
//   (ks 0..31, nf 0..15, n = nf*16 + l15 over [Wk|Wv] concat)

// ---------------------------------------------------------------------------
// Kernel 0: prep — [Wk|Wv] f32 -> bf16 B-fragment-major Wfrag (512 KB).
// ---------------------------------------------------------------------------
__global__ void __launch_bounds__(256) prep_kernel(
    const float* __restrict__ Wk, const float* __restrict__ Wv,
    u16* __restrict__ Wfrag)
{
  int T = blockIdx.x * 256 + threadIdx.x;   // 0..32767
  int lane = T & 63;
  int nf   = (T >> 6) & 15;
  int ks   = T >> 10;                       // 0..31
  int l15  = lane & 15;
  int g    = lane >> 4;
  int n    = nf * 16 + l15;
  const float* src = (n < 128) ? (Wk + n) : (Wv + (n - 128));
  int k0 = ks * 32 + g * 8;
  U128 w;
#pragma unroll
  for (int j = 0; j < 8; ++j) w.us[j] = f2bf(src[(size_t)(k0 + j) * KSZ]);
  *(uint4*)(Wfrag + (size_t)T * 8) = w.u4;
}

// ---------------------------------------------------------------------------
// Kernel 1: X-stationary GEMM — 2 barriers total, ZERO global_load_lds.
// (R6..R11 invariant: every glds+barrier-phase structure lands ~50us with
//  all pipes idle; plain-load wave-autonomous kernels (attn/cvt) run at BW.)
// Grid 256 (=1 block/CU), 256 thr (4 waves). Phase 1: cvt-style contiguous
// stage of the 64-row X block into LDS (f32->bf16, XOR-swizzled). Barrier.
// Phase 2: per-wave autonomous K-loop: wave w owns cols w*64..w*64+63;
// per ks: 4 ds_read_b128 A-frags + 4 plain 1KB W-frag loads (dbuf wfA/wfB,
// issued ahead of the MFMAs that hide them) + 16 mfma16. Barrier.
// Epilogue: per-wave LDS scratch (reuses X area) -> frag-major K/V stores.
// ---------------------------------------------------------------------------
__global__ void __launch_bounds__(256, 1) gemm_kernel(
    const float* __restrict__ X, const u16* __restrict__ Wfrag,
    const float* __restrict__ bk, const float* __restrict__ bv,
    u16* __restrict__ Kfrag, u16* __restrict__ Vfrag)
{
  __shared__ u16 Xl[64 * 1024];   // 128 KB: X block bf16, XOR-swizzled rows

  const int tid  = threadIdx.x;
  const int lane = tid & 63;
  const int w    = tid >> 6;      // 0..3: wave = 64-col strip
  const int l15  = lane & 15;
  const int g    = lane >> 4;
  const int m0   = blockIdx.x * 64;

  // ---- Phase 1: stage X block (cvt-style contiguous; 6.9 TB/s pattern) ----
  {
    const int u   = tid & 127;        // 32B granule within row
    const int ro  = tid >> 7;         // 0..1
#pragma unroll
    for (int h = 0; h < 4; ++h) {
      float4 t0[8], t1[8];
#pragma unroll
      for (int p = 0; p < 8; ++p) {
        int row = (h * 8 + p) * 2 + ro;
        const float4* xp = (const float4*)(X + (size_t)(m0 + row) * DMS + u * 8);
        t0[p] = xp[0]; t1[p] = xp[1];
      }
#pragma unroll
      for (int p = 0; p < 8; ++p) {
        int row = (h * 8 + p) * 2 + ro;
        *(uint4*)(Xl + row * 1024 + ((u * 8) ^ ((row & 7) << 3))) =
            pack8bf(t0[p], t1[p]);
      }
    }
  }
  __syncthreads();

  // ---- Phase 2: wave-autonomous K-loop ----
  f32x4 acc[4][4];
#pragma unroll
  for (int i = 0; i < 4; ++i)
#pragma unroll
    for (int j = 0; j < 4; ++j) acc[i][j] = (f32x4){0.f, 0.f, 0.f, 0.f};

  const u16* wbase = Wfrag + (w * 4) * 512 + lane * 8;   // + ks*8192 + nf*512

  bf16x8 wfA[4], wfB[4];
#pragma unroll
  for (int nf = 0; nf < 4; ++nf) {
    U128 u; u.u4 = *(const uint4*)(wbase + nf * 512); wfA[nf] = u.b8;
  }

#pragma unroll
  for (int k2 = 0; k2 < 16; ++k2) {
    // ---- even ks = 2*k2: load wfB(2*k2+1) early, compute with wfA ----
    {
      const int ksn = 2 * k2 + 1;
#pragma unroll
      for (int nf = 0; nf < 4; ++nf) {
        U128 u; u.u4 = *(const uint4*)(wbase + (size_t)ksn * 8192 + nf * 512);
        wfB[nf] = u.b8;
      }
      const int ks = 2 * k2;
      bf16x8 af[4];
#pragma unroll
      for (int mf = 0; mf < 4; ++mf) {
        int m = mf * 16 + l15;
        U128 u; u.u4 = *(const uint4*)(Xl + m * 1024 +
                                       ((ks * 32 + g * 8) ^ ((m & 7) << 3)));
        af[mf] = u.b8;
      }
#pragma unroll
      for (int mf = 0; mf < 4; ++mf)
#pragma unroll
        for (int nf = 0; nf < 4; ++nf)
          acc[mf][nf] = mfma16(af[mf], wfA[nf], acc[mf][nf]);
    }
    // ---- odd ks = 2*k2+1: load wfA(2*k2+2) early, compute with wfB ----
    {
      const int ksn = (k2 < 15) ? 2 * k2 + 2 : 0;
#pragma unroll
      for (int nf = 0; nf < 4; ++nf) {
        U128 u; u.u4 = *(const uint4*)(wbase + (size_t)ksn * 8192 + nf * 512);
        wfA[nf] = u.b8;
      }
      const int ks = 2 * k2 + 1;
      bf16x8 af[4];
#pragma unroll
      for (int mf = 0; mf < 4; ++mf) {
        int m = mf * 16 + l15;
        U128 u; u.u4 = *(const uint4*)(Xl + m * 1024 +
                                       ((ks * 32 + g * 8) ^ ((m & 7) << 3)));
        af[mf] = u.b8;
      }
#pragma unroll
      for (int mf = 0; mf < 4; ++mf)
#pragma unroll
        for (int nf = 0; nf < 4; ++nf)
          acc[mf][nf] = mfma16(af[mf], wfB[nf], acc[mf][nf]);
    }
  }

  __syncthreads();   // all Xl reads done; reuse as per-wave C scratch

  // ---- epilogue: bias + per-wave col-swizzled C[64][64] in LDS ----
  u16* Cw = Xl + w * 4096;   // 8 KB per wave
  {
    float bias[4];
#pragma unroll
    for (int nf = 0; nf < 4; ++nf) {
      int n = w * 64 + nf * 16 + l15;
      bias[nf] = (n < 128) ? bk[n] : bv[n - 128];
    }
#pragma unroll
    for (int nf = 0; nf < 4; ++nf)
#pragma unroll
      for (int mf = 0; mf < 4; ++mf)
#pragma unroll
        for (int j = 0; j < 4; ++j) {
          int s = mf * 16 + g * 4 + j;
          int c = nf * 16 + l15;
          Cw[s * 64 + (c ^ ((s & 7) << 3))] = f2bf(acc[mf][nf][j] + bias[nf]);
        }
  }
  // same-wave ds_write -> ds_read: compiler orders via lgkmcnt

  const int bb   = m0 >> 11;            // batch
  const int tloc = (m0 & 2047) >> 5;    // first 32-row tile within batch

  if (w < 2) {
    // ---- Kfrag stores: lane = block row sl ----
    const int sl  = lane;
    const int t2  = tloc + (sl >> 5);
    const int l31 = sl & 31;
#pragma unroll
    for (int kc = 0; kc < 4; ++kc) {
      int ks2 = w * 4 + kc;
      u16* dst = Kfrag + (size_t)bb * BSTRIDE + (size_t)(t2 * 8 + ks2) * 512 + l31 * 8;
#pragma unroll
      for (int hi2 = 0; hi2 < 2; ++hi2) {
        uint4 v = *(const uint4*)&Cw[sl * 64 + ((kc * 16 + hi2 * 8) ^ ((sl & 7) << 3))];
        *(uint4*)(dst + hi2 * 256) = v;
      }
    }
  } else {
    // ---- Vfrag stores (transpose out of Cw) ----
    const int l31v   = lane & 31;
    const int vb2loc = lane >> 5;
    const int vb2    = (w - 2) * 2 + vb2loc;
    const int ccol   = vb2loc * 32 + l31v;
#pragma unroll
    for (int p = 0; p < 2; ++p) {
      int t2 = tloc + p;
#pragma unroll
      for (int th = 0; th < 2; ++th)
#pragma unroll
        for (int hi = 0; hi < 2; ++hi) {
          U128 wv;
#pragma unroll
          for (int j = 0; j < 8; ++j) {
            int s = p * 32 + th * 16 + hi * 8 + j;
            wv.us[j] = Cw[s * 64 + (ccol ^ ((s & 7) << 3))];
          }
          u16* dst = Vfrag + (size_t)bb * BSTRIDE +
                     (size_t)((t2 * 4 + vb2) * 2 + th) * 512 + hi * 256 + l31v * 8;
          *(uint4*)dst = wv.u4;
        }
    }
  }
}

// ---------------------------------------------------------------------------
// Kernel 2: causal flash attention + TAIL passthrough copy (unchanged R9-R11).
// ---------------------------------------------------------------------------
__global__ void __launch_bounds__(256, 2) attn_kernel(
    const u16* __restrict__ Kfrag, const u16* __restrict__ Vfrag,
    const float* __restrict__ X, float* __restrict__ out)
{
  __shared__ float Om[4][128][33];   // [slice][v][q] partial O^T
  __shared__ float Ml[4][2][32];     // [slice][m|l][q]
  __shared__ float Wm[4][32];        // merge weights
  __shared__ float Li[32];           // 1/L

  const int tid  = threadIdx.x;
  const int lane = tid & 63;
  const int w    = tid >> 6;         // KV slice 0..3
  const int l31  = lane & 31;
  const int hi   = lane >> 5;

  const int bi = blockIdx.x;
  const int b  = bi & 7;
  const int qt = (bi < 256) ? (63 - (bi >> 3)) : ((bi >> 3) - 32);
  const int q0 = qt * 32;

  const u16* Kb = Kfrag + (size_t)b * BSTRIDE;
  const u16* Vb = Vfrag + (size_t)b * BSTRIDE;
  const int loff = hi * 256 + l31 * 8;   // lane offset within a 512-u16 frag

  bf16x8 qf[8];
  {
    const u16* qp = Kb + (size_t)(qt * 8) * 512 + loff;
#pragma unroll
    for (int ks = 0; ks < 8; ++ks) {
      U128 u; u.u4 = *(const uint4*)(qp + ks * 512); qf[ks] = u.b8;
    }
  }

  f32x16 o[4];
#pragma unroll
  for (int vb2 = 0; vb2 < 4; ++vb2)
#pragma unroll
    for (int i = 0; i < 16; ++i) o[vb2][i] = 0.f;

  float mrun = -3.0e38f, lsum = 0.f;
  const float SC  = 0.08838834764831845f;   // 1/sqrt(128)
  const float L2E = 1.44269504088896341f;

  bf16x8 kf[8];
  {
    int ti0 = (w <= qt) ? w : 0;
    const u16* kp = Kb + (size_t)(ti0 * 8) * 512 + loff;
#pragma unroll
    for (int ks = 0; ks < 8; ++ks) {
      U128 u; u.u4 = *(const uint4*)(kp + ks * 512); kf[ks] = u.b8;
    }
  }

  for (int ti = w; ti <= qt; ti += 4) {
    bf16x8 vf[4][2];
    {
      const u16* vp = Vb + (size_t)(ti * 8) * 512 + loff;
#pragma unroll
      for (int vb2 = 0; vb2 < 4; ++vb2)
#pragma unroll
        for (int th = 0; th < 2; ++th) {
          U128 u; u.u4 = *(const uint4*)(vp + (vb2 * 2 + th) * 512);
          vf[vb2][th] = u.b8;
        }
    }
    f32x16 s;
#pragma unroll
    for (int i = 0; i < 16; ++i) s[i] = 0.f;
#pragma unroll
    for (int ks = 0; ks < 8; ++ks) s = mfma32(kf[ks], qf[ks], s);
    {
      int tin = (ti + 4 <= qt) ? ti + 4 : ti;
      const u16* kp = Kb + (size_t)(tin * 8) * 512 + loff;
#pragma unroll
      for (int ks = 0; ks < 8; ++ks) {
        U128 u; u.u4 = *(const uint4*)(kp + ks * 512); kf[ks] = u.b8;
      }
    }
    float sv[16];
#pragma unroll
    for (int r = 0; r < 16; ++r) sv[r] = s[r] * SC;
    if (ti == qt) {
#pragma unroll
      for (int r = 0; r < 16; ++r) {
        int toff = (r & 3) + 8 * (r >> 2) + 4 * hi;
        if (toff > l31) sv[r] = -3.0e38f;
      }
    }
    float mx = sv[0];
#pragma unroll
    for (int r = 1; r < 16; ++r) mx = fmaxf(mx, sv[r]);
    mx = fmaxf(mx, __shfl_xor(mx, 32));
    float p[16];
    float ps = 0.f;
    if (__all(mx - mrun <= 8.0f)) {
#pragma unroll
      for (int r = 0; r < 16; ++r) { p[r] = fexp2((sv[r] - mrun) * L2E); ps += p[r]; }
      ps += __shfl_xor(ps, 32);
      lsum += ps;
    } else {
      float mnew = fmaxf(mrun, mx);
      float al = fexp2((mrun - mnew) * L2E);
#pragma unroll
      for (int r = 0; r < 16; ++r) { p[r] = fexp2((sv[r] - mnew) * L2E); ps += p[r]; }
      ps += __shfl_xor(ps, 32);
      lsum = lsum * al + ps;
      mrun = mnew;
#pragma unroll
      for (int vb2 = 0; vb2 < 4; ++vb2)
#pragma unroll
        for (int i = 0; i < 16; ++i) o[vb2][i] *= al;
    }
    u32 c01 = (u32)f2bf(p[0])  | ((u32)f2bf(p[1])  << 16);
    u32 c23 = (u32)f2bf(p[2])  | ((u32)f2bf(p[3])  << 16);
    u32 c45 = (u32)f2bf(p[4])  | ((u32)f2bf(p[5])  << 16);
    u32 c67 = (u32)f2bf(p[6])  | ((u32)f2bf(p[7])  << 16);
    u32 c89 = (u32)f2bf(p[8])  | ((u32)f2bf(p[9])  << 16);
    u32 cAB = (u32)f2bf(p[10]) | ((u32)f2bf(p[11]) << 16);
    u32 cCD = (u32)f2bf(p[12]) | ((u32)f2bf(p[13]) << 16);
    u32 cEF = (u32)f2bf(p[14]) | ((u32)f2bf(p[15]) << 16);
    u32 d01 = __shfl_xor(c01, 32);
    u32 d23 = __shfl_xor(c23, 32);
    u32 d45 = __shfl_xor(c45, 32);
    u32 d67 = __shfl_xor(c67, 32);
    u32 d89 = __shfl_xor(c89, 32);
    u32 dAB = __shfl_xor(cAB, 32);
    u32 dCD = __shfl_xor(cCD, 32);
    u32 dEF = __shfl_xor(cEF, 32);
    U128 pf1, pf2;
    pf1.u[0] = hi ? d45 : c01;
    pf1.u[1] = hi ? d67 : c23;
    pf1.u[2] = hi ? c45 : d01;
    pf1.u[3] = hi ? c67 : d23;
    pf2.u[0] = hi ? dCD : c89;
    pf2.u[1] = hi ? dEF : cAB;
    pf2.u[2] = hi ? cCD : d89;
    pf2.u[3] = hi ? cEF : dAB;
#pragma unroll
    for (int vb2 = 0; vb2 < 4; ++vb2) {
      o[vb2] = mfma32(vf[vb2][0], pf1.b8, o[vb2]);
      o[vb2] = mfma32(vf[vb2][1], pf2.b8, o[vb2]);
    }
  }

  // ---- publish partials ----
#pragma unroll
  for (int vb2 = 0; vb2 < 4; ++vb2)
#pragma unroll
    for (int r = 0; r < 16; ++r) {
      int v = vb2 * 32 + (r & 3) + 8 * (r >> 2) + 4 * hi;
      Om[w][v][l31] = o[vb2][r];
    }
  if (lane < 32) {
    Ml[w][0][l31] = mrun;
    Ml[w][1][l31] = lsum;
  }
  __syncthreads();

  if (tid < 32) {
    float m0 = Ml[0][0][tid], m1 = Ml[1][0][tid];
    float m2 = Ml[2][0][tid], m3 = Ml[3][0][tid];
    float M  = fmaxf(fmaxf(m0, m1), fmaxf(m2, m3));
    float w0 = fexp2((m0 - M) * L2E), w1 = fexp2((m1 - M) * L2E);
    float w2 = fexp2((m2 - M) * L2E), w3 = fexp2((m3 - M) * L2E);
    float L  = Ml[0][1][tid] * w0 + Ml[1][1][tid] * w1 +
               Ml[2][1][tid] * w2 + Ml[3][1][tid] * w3;
    Wm[0][tid] = w0; Wm[1][tid] = w1; Wm[2][tid] = w2; Wm[3][tid] = w3;
    Li[tid] = 1.f / L;
  }
  __syncthreads();

  {
    const int q = tid >> 3;
    const int vbase = (tid & 7) * 16;
    float wq0 = Wm[0][q], wq1 = Wm[1][q], wq2 = Wm[2][q], wq3 = Wm[3][q];
    float li = Li[q];
    float* orow = out + (size_t)(b * SEQ + q0 + q) * OD + 1024 + vbase;
#pragma unroll
    for (int i = 0; i < 16; i += 4) {
      float4 res;
      res.x = (Om[0][vbase + i + 0][q] * wq0 + Om[1][vbase + i + 0][q] * wq1 +
               Om[2][vbase + i + 0][q] * wq2 + Om[3][vbase + i + 0][q] * wq3) * li;
      res.y = (Om[0][vbase + i + 1][q] * wq0 + Om[1][vbase + i + 1][q] * wq1 +
               Om[2][vbase + i + 1][q] * wq2 + Om[3][vbase + i + 1][q] * wq3) * li;
      res.z = (Om[0][vbase + i + 2][q] * wq0 + Om[1][vbase + i + 2][q] * wq1 +
               Om[2][vbase + i + 2][q] * wq2 + Om[3][vbase + i + 2][q] * wq3) * li;
      res.w = (Om[0][vbase + i + 3][q] * wq0 + Om[1][vbase + i + 3][q] * wq1 +
               Om[2][vbase + i + 3][q] * wq2 + Om[3][vbase + i + 3][q] * wq3) * li;
      *(float4*)(orow + i) = res;
    }
  }

  // ---- TAIL passthrough copy: out[:, :1024] = X for this block's 32 rows ----
  {
#pragma unroll
    for (int r0 = 0; r0 < 32; r0 += 8) {
      float4 t[8];
#pragma unroll
      for (int j = 0; j < 8; ++j)
        t[j] = *((const float4*)(X + (size_t)(b * SEQ + q0 + r0 + j) * DMS) + tid);
#pragma unroll
      for (int j = 0; j < 8; ++j)
        *((float4*)(out + (size_t)(b * SEQ + q0 + r0 + j) * OD) + tid) = t[j];
    }
  }
}

extern "C" void kernel_launch(void* const* d_in, const int* in_sizes, int n_in,
                              void* d_out, int out_size, void* d_ws, size_t ws_size,
                              hipStream_t stream)
{
  const float* X  = (const float*)d_in[0];
  const float* Wk = (const float*)d_in[1];
  const float* bk = (const float*)d_in[2];
  const float* Wv = (const float*)d_in[3];
  const float* bv = (const float*)d_in[4];
  float* out = (float*)d_out;

  u16* Kfrag = (u16*)d_ws;                                 // 4 MB
  u16* Vfrag = Kfrag + (size_t)BATCH * BSTRIDE;            // 4 MB
  u16* Wfrag = Vfrag + (size_t)BATCH * BSTRIDE;            // 512 KB

  prep_kernel<<<dim3(128), dim3(256), 0, stream>>>(Wk, Wv, Wfrag);
  gemm_kernel<<<dim3(256), dim3(256), 0, stream>>>(X, Wfrag, bk, bv, Kfrag, Vfrag);
  attn_kernel<<<dim3(512), dim3(256), 0, stream>>>(Kfrag, Vfrag, X, out);
}